// Round 13
// baseline (9636.268 us; speedup 1.0000x reference)
//
#include <hip/hip_runtime.h>
#include <hip/hip_bf16.h>

// GRU tagger. T=2048, E=H=1024, 3H=3072, TAGS=50.
// R13: merged poll+fetch. Embedded self-validating {h,step} pairs (producer =
//      ONE fire-and-forget 8B store, no drain-then-tag, no bottom barrier) +
//      wave0-only polling (R10's contention fix) where the detection load IS
//      the data load (8x dwordx4 per lane, single vmcnt per retry).
//      Weights 96 fp32/thread, in-loop asm pin (R8-proven residency).

#define T_SEQ 2048
#define E_DIM 1024
#define H_DIM 1024
#define N3H   3072
#define VTAGS 50
#define VOCAB 50257
#define NWG   64
#define IPW   (H_DIM / NWG)   // 16 h-rows per workgroup
#define SBLK  512

typedef short bf16x8 __attribute__((ext_vector_type(8)));
typedef float f32x4  __attribute__((ext_vector_type(4)));
typedef unsigned int u32x4v __attribute__((ext_vector_type(4)));

__device__ inline unsigned short f2bf_rne(float f) {
  unsigned int u = __float_as_uint(f);
  u += 0x7FFFu + ((u >> 16) & 1u);
  return (unsigned short)(u >> 16);
}

// ---------------- embedding gather + cast to bf16 ----------------
__global__ __launch_bounds__(256) void k_gather_cast(
    const int* __restrict__ sent, const float* __restrict__ emb,
    unsigned short* __restrict__ Xb) {
  const int t = blockIdx.x;
  int row = sent[t];
  row = (row < 0) ? 0 : ((row >= VOCAB) ? VOCAB - 1 : row);
  const float4* src = (const float4*)(emb + (size_t)row * E_DIM);
  float4 v = src[threadIdx.x];
  ushort4 o;
  o.x = f2bf_rne(v.x); o.y = f2bf_rne(v.y); o.z = f2bf_rne(v.z); o.w = f2bf_rne(v.w);
  ((ushort4*)(Xb + (size_t)t * E_DIM))[threadIdx.x] = o;
}

__global__ __launch_bounds__(256) void k_cast_w(
    const float* __restrict__ W, unsigned short* __restrict__ Wb) {
  const int r = blockIdx.x;
  const float4* src = (const float4*)(W + (size_t)r * E_DIM);
  float4 v = src[threadIdx.x];
  ushort4 o;
  o.x = f2bf_rne(v.x); o.y = f2bf_rne(v.y); o.z = f2bf_rne(v.z); o.w = f2bf_rne(v.w);
  ((ushort4*)(Wb + (size_t)r * E_DIM))[threadIdx.x] = o;
}

// ---------------- gi = X @ W_ih^T + b_ih  (bf16 MFMA, fp32 accum) ----------------
__global__ __launch_bounds__(256) void k_gemm_gi(
    const unsigned short* __restrict__ Xb, const unsigned short* __restrict__ Wb,
    const float* __restrict__ b_ih, float* __restrict__ gi) {
  const int tid = threadIdx.x;
  const int lane = tid & 63;
  const int wv = tid >> 6;
  const int m_base = blockIdx.y * 128 + (wv & 1) * 64;
  const int n_base = blockIdx.x * 128 + (wv >> 1) * 64;
  const int lr = lane & 15;
  const int kq = (lane >> 4) * 8;
  f32x4 acc[4][4] = {};
  for (int k0 = 0; k0 < E_DIM; k0 += 32) {
    bf16x8 a[4], b[4];
#pragma unroll
    for (int mi = 0; mi < 4; ++mi)
      a[mi] = *(const bf16x8*)(Xb + (size_t)(m_base + mi * 16 + lr) * E_DIM + k0 + kq);
#pragma unroll
    for (int ni = 0; ni < 4; ++ni)
      b[ni] = *(const bf16x8*)(Wb + (size_t)(n_base + ni * 16 + lr) * E_DIM + k0 + kq);
#pragma unroll
    for (int mi = 0; mi < 4; ++mi)
#pragma unroll
      for (int ni = 0; ni < 4; ++ni)
        acc[mi][ni] = __builtin_amdgcn_mfma_f32_16x16x32_bf16(a[mi], b[ni], acc[mi][ni], 0, 0, 0);
  }
  const int row_q = (lane >> 4) * 4;
#pragma unroll
  for (int mi = 0; mi < 4; ++mi) {
#pragma unroll
    for (int ni = 0; ni < 4; ++ni) {
      const int col  = n_base + ni * 16 + lr;
      const int row0 = m_base + mi * 16 + row_q;
      const float bv = b_ih[col];
#pragma unroll
      for (int rr = 0; rr < 4; ++rr)
        gi[(size_t)(row0 + rr) * N3H + col] = acc[mi][ni][rr] + bv;
    }
  }
}

// ---------------- persistent GRU scan (embedded pairs, wave0 poll+fetch) ----------------
// 64 WGs x 512 thr. Thread (row=tid>>5 in 0..15, cg=tid&31): 96 weight floats
// (cols {4cg+128q+k}) pinned in VGPRs every iteration.
// mb[2][1024] {f32 h (lo), u32 step (hi)}, double-buffered by parity.
// Per step t: wave0 polls+fetches its 16 pairs (lane: 8x dwordx4 sc0 sc1 issued
// together, one vmcnt) until all 16 tags == t; repacks h -> LDS; B1; all threads
// 96 FMA + 32-lane butterfly + gates; cg==0 stores {h, t+1} pair (single 8B
// atomic store, fire-and-forget). NO bottom barrier.
// Two-phase safety (single-barrier proof): slot s=t&1 is next overwritten at
// iteration t+1 by leaders that passed poll(t+1) (all tags t+1 seen), and any
// WG v's reads of slot s (v.wave0 poll(t)) precede v's tag-t+1 stores, which
// precede every WG's poll(t+1) success -> overwrite happens-after all reads.
// LDS slot s is overwritten at step t+2 by wave0 pre-B1(t+2); readers of s
// (compute(t)) all passed B1(t+1) first. No fences needed anywhere.
__global__ __launch_bounds__(SBLK) __attribute__((amdgpu_waves_per_eu(2, 2)))
void k_gru_scan(const float* __restrict__ W_hh, const float* __restrict__ b_hh,
                const float* __restrict__ gi, float* __restrict__ hs,
                unsigned long long* mb) {
  const int wg  = blockIdx.x;
  const int tid = threadIdx.x;
  const int row = tid >> 5;        // 0..15 : h-row within WG
  const int cg  = tid & 31;        // 0..31 : column group
  const int lane = tid & 63;
  const int i   = wg * IPW + row;  // global h row

  __shared__ float hsh[2][H_DIM];

  // 96 weight floats: cols {4cg + 128q + k} of rows {i, H+i, 2H+i}
  f32x4 w0[8], w1[8], w2[8];
  {
    const f32x4* p0 = (const f32x4*)(W_hh + (size_t)i * H_DIM);
    const f32x4* p1 = (const f32x4*)(W_hh + (size_t)(H_DIM + i) * H_DIM);
    const f32x4* p2 = (const f32x4*)(W_hh + (size_t)(2 * H_DIM + i) * H_DIM);
#pragma unroll
    for (int q = 0; q < 8; ++q) {
      w0[q] = p0[cg + q * 32];
      w1[q] = p1[cg + q * 32];
      w2[q] = p2[cg + q * 32];
    }
  }
  const float bh0 = b_hh[i], bh1 = b_hh[H_DIM + i], bh2 = b_hh[2 * H_DIM + i];

  for (int t = 0; t < T_SEQ; ++t) {
    // pin weights: asm "rewrites" them each iteration -> reload from W_hh illegal
    asm volatile("" : "+v"(w0[0]), "+v"(w0[1]), "+v"(w0[2]), "+v"(w0[3]),
                      "+v"(w0[4]), "+v"(w0[5]), "+v"(w0[6]), "+v"(w0[7]),
                      "+v"(w1[0]), "+v"(w1[1]), "+v"(w1[2]), "+v"(w1[3]),
                      "+v"(w1[4]), "+v"(w1[5]), "+v"(w1[6]), "+v"(w1[7]),
                      "+v"(w2[0]), "+v"(w2[1]), "+v"(w2[2]), "+v"(w2[3]),
                      "+v"(w2[4]), "+v"(w2[5]), "+v"(w2[6]), "+v"(w2[7]));

    // gi prefetch: issued before the poll/wait, completes under it
    const float gir = gi[(size_t)t * N3H + i];
    const float giz = gi[(size_t)t * N3H + H_DIM + i];
    const float gin = gi[(size_t)t * N3H + 2 * H_DIM + i];

    if (tid < 64) {
      // wave0: poll+fetch its 16 pairs of slot t&1 (128B/lane, 8 dwordx4/retry)
      const unsigned long long* pb = mb + (size_t)(t & 1) * H_DIM + lane * 16;
      const unsigned tt = (unsigned)t;
      u32x4v p0, p1, p2, p3, p4, p5, p6, p7;
      int it = 0;
      while (true) {
        asm volatile(
            "global_load_dwordx4 %0, %8, off sc0 sc1\n\t"
            "global_load_dwordx4 %1, %8, off offset:16 sc0 sc1\n\t"
            "global_load_dwordx4 %2, %8, off offset:32 sc0 sc1\n\t"
            "global_load_dwordx4 %3, %8, off offset:48 sc0 sc1\n\t"
            "global_load_dwordx4 %4, %8, off offset:64 sc0 sc1\n\t"
            "global_load_dwordx4 %5, %8, off offset:80 sc0 sc1\n\t"
            "global_load_dwordx4 %6, %8, off offset:96 sc0 sc1\n\t"
            "global_load_dwordx4 %7, %8, off offset:112 sc0 sc1\n\t"
            "s_waitcnt vmcnt(0)"
            : "=v"(p0), "=v"(p1), "=v"(p2), "=v"(p3),
              "=v"(p4), "=v"(p5), "=v"(p6), "=v"(p7)
            : "v"(pb));
        bool ok = (p0[1] == tt) & (p0[3] == tt) & (p1[1] == tt) & (p1[3] == tt) &
                  (p2[1] == tt) & (p2[3] == tt) & (p3[1] == tt) & (p3[3] == tt) &
                  (p4[1] == tt) & (p4[3] == tt) & (p5[1] == tt) & (p5[3] == tt) &
                  (p6[1] == tt) & (p6[3] == tt) & (p7[1] == tt) & (p7[3] == tt);
        if (__all(ok) || ++it > (1 << 16)) break;
      }
      // repack 16 h values -> 4x float4 -> LDS (consecutive b128, conflict-free)
      f32x4* hb4 = (f32x4*)hsh[t & 1];
      hb4[lane * 4 + 0] = f32x4{__uint_as_float(p0[0]), __uint_as_float(p0[2]),
                                __uint_as_float(p1[0]), __uint_as_float(p1[2])};
      hb4[lane * 4 + 1] = f32x4{__uint_as_float(p2[0]), __uint_as_float(p2[2]),
                                __uint_as_float(p3[0]), __uint_as_float(p3[2])};
      hb4[lane * 4 + 2] = f32x4{__uint_as_float(p4[0]), __uint_as_float(p4[2]),
                                __uint_as_float(p5[0]), __uint_as_float(p5[2])};
      hb4[lane * 4 + 3] = f32x4{__uint_as_float(p6[0]), __uint_as_float(p6[2]),
                                __uint_as_float(p7[0]), __uint_as_float(p7[2])};
    }
    __syncthreads();   // B1: h published to LDS (the only barrier per step)

    const float* hb = hsh[t & 1];
    const f32x4* hb4 = (const f32x4*)hb;
    float a0 = 0.f, a1 = 0.f, a2 = 0.f;
#pragma unroll
    for (int q = 0; q < 8; ++q) {
      f32x4 hv = hb4[cg + q * 32];   // 32 consecutive 16B slots: conflict-free
      a0 = fmaf(w0[q][0], hv[0], a0); a0 = fmaf(w0[q][1], hv[1], a0);
      a0 = fmaf(w0[q][2], hv[2], a0); a0 = fmaf(w0[q][3], hv[3], a0);
      a1 = fmaf(w1[q][0], hv[0], a1); a1 = fmaf(w1[q][1], hv[1], a1);
      a1 = fmaf(w1[q][2], hv[2], a1); a1 = fmaf(w1[q][3], hv[3], a1);
      a2 = fmaf(w2[q][0], hv[0], a2); a2 = fmaf(w2[q][1], hv[1], a2);
      a2 = fmaf(w2[q][2], hv[2], a2); a2 = fmaf(w2[q][3], hv[3], a2);
    }
#pragma unroll
    for (int off = 16; off >= 1; off >>= 1) {   // reduce across 32-lane group
      a0 += __shfl_xor(a0, off, 64);
      a1 += __shfl_xor(a1, off, 64);
      a2 += __shfl_xor(a2, off, 64);
    }
    const float r = 1.f / (1.f + __expf(-(gir + a0 + bh0)));
    const float z = 1.f / (1.f + __expf(-(giz + a1 + bh1)));
    const float nx = gin + r * (a2 + bh2);
    const float e2 = __expf(-2.f * fabsf(nx));
    float n = (1.f - e2) / (1.f + e2);
    n = (nx < 0.f) ? -n : n;
    const float hold = hb[i];
    const float hnew = (1.f - z) * n + z * hold;

    if (cg == 0) {
      const unsigned long long pack =
          ((unsigned long long)(unsigned)(t + 1) << 32) |
          (unsigned long long)__float_as_uint(hnew);
      __hip_atomic_store(&mb[(size_t)((t + 1) & 1) * H_DIM + i], pack,
                         __ATOMIC_RELAXED, __HIP_MEMORY_SCOPE_AGENT);
      hs[(size_t)t * H_DIM + i] = hnew;   // consumed by k_out after kernel end
    }
    // no bottom barrier: see two-phase safety proof in the kernel header
  }
}

// ---------------- tag head: hs @ W_out^T + b_out, log_softmax ----------------
__global__ __launch_bounds__(256) void k_out(
    const float* __restrict__ hs, const float* __restrict__ W_out,
    const float* __restrict__ b_out, float* __restrict__ out) {
  const int t = blockIdx.x;
  const int tid = threadIdx.x;
  const int wv = tid >> 6, lane = tid & 63;
  __shared__ float xs[H_DIM];
  __shared__ float tagv[64];
  ((float4*)xs)[tid] = ((const float4*)(hs + (size_t)t * H_DIM))[tid];
  __syncthreads();
  for (int g = wv; g < VTAGS; g += 4) {
    const float4* wr = (const float4*)(W_out + (size_t)g * H_DIM);
    const float4* xr = (const float4*)xs;
    float s = 0.f;
#pragma unroll
    for (int q = 0; q < 4; ++q) {
      float4 a = wr[lane * 4 + q];
      float4 b = xr[lane * 4 + q];
      s += a.x * b.x + a.y * b.y + a.z * b.z + a.w * b.w;
    }
#pragma unroll
    for (int off = 1; off < 64; off <<= 1) s += __shfl_xor(s, off, 64);
    if (lane == 0) tagv[g] = s + b_out[g];
  }
  __syncthreads();
  if (tid < 64) {
    const float v = (tid < VTAGS) ? tagv[tid] : -1e30f;
    float m = v;
#pragma unroll
    for (int off = 1; off < 64; off <<= 1) m = fmaxf(m, __shfl_xor(m, off, 64));
    float e = (tid < VTAGS) ? __expf(v - m) : 0.f;
    float se = e;
#pragma unroll
    for (int off = 1; off < 64; off <<= 1) se += __shfl_xor(se, off, 64);
    const float lse = logf(se);
    if (tid < VTAGS) out[(size_t)t * VTAGS + tid] = v - m - lse;
  }
}

extern "C" void kernel_launch(void* const* d_in, const int* in_sizes, int n_in,
                              void* d_out, int out_size, void* d_ws, size_t ws_size,
                              hipStream_t stream) {
  const int* sent    = (const int*)d_in[0];
  const float* emb   = (const float*)d_in[1];
  const float* W_ih  = (const float*)d_in[2];
  const float* W_hh  = (const float*)d_in[3];
  const float* b_ih  = (const float*)d_in[4];
  const float* b_hh  = (const float*)d_in[5];
  const float* W_out = (const float*)d_in[6];
  const float* b_out = (const float*)d_in[7];
  float* out = (float*)d_out;

  char* ws = (char*)d_ws;
  const size_t OFF_GI = 0;
  const size_t OFF_B  = (size_t)T_SEQ * N3H * 4;            // 24 MB
  const size_t OFF_XB = OFF_B;
  const size_t OFF_WB = OFF_B + (size_t)T_SEQ * E_DIM * 2;  // +4 MB
  const size_t OFF_HS = OFF_B;                              // reuse after GEMM
  const size_t OFF_MB = OFF_B + 10485760;                   // mb[2][1024] pairs
  const size_t NEED = OFF_MB + 2 * H_DIM * 8;
  if (ws_size < NEED) return;

  float* gi = (float*)(ws + OFF_GI);
  unsigned short* Xb = (unsigned short*)(ws + OFF_XB);
  unsigned short* Wb = (unsigned short*)(ws + OFF_WB);
  float* hs = (float*)(ws + OFF_HS);
  unsigned long long* mb = (unsigned long long*)(ws + OFF_MB);

  // zero mailbox: tags=0 == step 0, h0=0  (re-run on every graph replay)
  (void)hipMemsetAsync(mb, 0, 2 * H_DIM * 8, stream);

  k_gather_cast<<<T_SEQ, 256, 0, stream>>>(sent, emb, Xb);
  k_cast_w<<<N3H, 256, 0, stream>>>(W_ih, Wb);
  k_gemm_gi<<<dim3(N3H / 128, T_SEQ / 128), 256, 0, stream>>>(Xb, Wb, b_ih, gi);
  k_gru_scan<<<NWG, SBLK, 0, stream>>>(W_hh, b_hh, gi, hs, mb);
  k_out<<<T_SEQ, 256, 0, stream>>>(hs, W_out, b_out, out);
}

// Round 14
// 8817.683 us; speedup vs baseline: 1.0928x; 1.0928x over previous
//
#include <hip/hip_runtime.h>
#include <hip/hip_bf16.h>

// GRU tagger. T=2048, E=H=1024, 3H=3072, TAGS=50.
// R14: software-pipelined poller wave on the R10 split-mailbox protocol.
//      Block=576: wave0 = dedicated tag-poller + data-fetcher; waves 1-8 = R10's
//      512 compute threads (identical arithmetic). ONE textual barrier/step:
//        phase A: compute waves store h(t) [carried in reg], self-drain vmcnt,
//                 LDS wave-counter releases per-WG tag  — CONCURRENT with wave0
//                 spinning on all 64 tags, then fetching h(t) and publishing LDS.
//        phase B: compute waves read LDS, FMA+reduce+gates -> h(t+1) in reg.
//      hs store moved after the drain (out of the critical path).

#define T_SEQ 2048
#define E_DIM 1024
#define H_DIM 1024
#define N3H   3072
#define VTAGS 50
#define VOCAB 50257
#define NWG   64
#define IPW   (H_DIM / NWG)   // 16 h-rows per workgroup
#define SBLK  576             // 1 poller wave + 8 compute waves

typedef short bf16x8 __attribute__((ext_vector_type(8)));
typedef float f32x4  __attribute__((ext_vector_type(4)));

__device__ inline unsigned short f2bf_rne(float f) {
  unsigned int u = __float_as_uint(f);
  u += 0x7FFFu + ((u >> 16) & 1u);
  return (unsigned short)(u >> 16);
}

// ---------------- embedding gather + cast to bf16 ----------------
__global__ __launch_bounds__(256) void k_gather_cast(
    const int* __restrict__ sent, const float* __restrict__ emb,
    unsigned short* __restrict__ Xb) {
  const int t = blockIdx.x;
  int row = sent[t];
  row = (row < 0) ? 0 : ((row >= VOCAB) ? VOCAB - 1 : row);
  const float4* src = (const float4*)(emb + (size_t)row * E_DIM);
  float4 v = src[threadIdx.x];
  ushort4 o;
  o.x = f2bf_rne(v.x); o.y = f2bf_rne(v.y); o.z = f2bf_rne(v.z); o.w = f2bf_rne(v.w);
  ((ushort4*)(Xb + (size_t)t * E_DIM))[threadIdx.x] = o;
}

__global__ __launch_bounds__(256) void k_cast_w(
    const float* __restrict__ W, unsigned short* __restrict__ Wb) {
  const int r = blockIdx.x;
  const float4* src = (const float4*)(W + (size_t)r * E_DIM);
  float4 v = src[threadIdx.x];
  ushort4 o;
  o.x = f2bf_rne(v.x); o.y = f2bf_rne(v.y); o.z = f2bf_rne(v.z); o.w = f2bf_rne(v.w);
  ((ushort4*)(Wb + (size_t)r * E_DIM))[threadIdx.x] = o;
}

// ---------------- gi = X @ W_ih^T + b_ih  (bf16 MFMA, fp32 accum) ----------------
__global__ __launch_bounds__(256) void k_gemm_gi(
    const unsigned short* __restrict__ Xb, const unsigned short* __restrict__ Wb,
    const float* __restrict__ b_ih, float* __restrict__ gi) {
  const int tid = threadIdx.x;
  const int lane = tid & 63;
  const int wv = tid >> 6;
  const int m_base = blockIdx.y * 128 + (wv & 1) * 64;
  const int n_base = blockIdx.x * 128 + (wv >> 1) * 64;
  const int lr = lane & 15;
  const int kq = (lane >> 4) * 8;
  f32x4 acc[4][4] = {};
  for (int k0 = 0; k0 < E_DIM; k0 += 32) {
    bf16x8 a[4], b[4];
#pragma unroll
    for (int mi = 0; mi < 4; ++mi)
      a[mi] = *(const bf16x8*)(Xb + (size_t)(m_base + mi * 16 + lr) * E_DIM + k0 + kq);
#pragma unroll
    for (int ni = 0; ni < 4; ++ni)
      b[ni] = *(const bf16x8*)(Wb + (size_t)(n_base + ni * 16 + lr) * E_DIM + k0 + kq);
#pragma unroll
    for (int mi = 0; mi < 4; ++mi)
#pragma unroll
      for (int ni = 0; ni < 4; ++ni)
        acc[mi][ni] = __builtin_amdgcn_mfma_f32_16x16x32_bf16(a[mi], b[ni], acc[mi][ni], 0, 0, 0);
  }
  const int row_q = (lane >> 4) * 4;
#pragma unroll
  for (int mi = 0; mi < 4; ++mi) {
#pragma unroll
    for (int ni = 0; ni < 4; ++ni) {
      const int col  = n_base + ni * 16 + lr;
      const int row0 = m_base + mi * 16 + row_q;
      const float bv = b_ih[col];
#pragma unroll
      for (int rr = 0; rr < 4; ++rr)
        gi[(size_t)(row0 + rr) * N3H + col] = acc[mi][ni][rr] + bv;
    }
  }
}

// ---------------- persistent GRU scan (pipelined poller wave) ----------------
// Slot s&1 of data[] holds h_s (h_0 = memset zeros, tag 0).
// Iteration t, phase A:
//   compute waves (t>0): cg==0 stores data[t&1][i]=h_t (reg-carried); wave
//     drains vmcnt(0); lane0 of each wave bumps LDS cnt[t&1]; 8th wave resets
//     cnt and stores tags[t&1][wg]=t; cg==0 then stores hs[t-1] (post-drain).
//   wave0: polls all 64 tags[t&1]==t (2 lines/retry, already spinning while
//     producers drain) -> fetches 1024 floats (16/lane) -> publishes LDS[t&1].
// barrier. Phase B: compute waves read LDS[t&1]=h_t, 96 FMA + 32-lane butterfly
//   + gates -> h_{t+1} kept in register. Epilogue stores hs[T-1].
// Safety: slot p=t&1 rewritten at t+2 phase A, after B(t+1), after every WG's
//   tag(t+1), after their B(t), after their wave0 fetch of p. LDS[p] rewritten
//   at t+2 after B(t+1); readers of p finished before B(t+1). cnt[p] reset at
//   phase A(t), reused A(t+2), ordered by B(t), B(t+1).
__global__ __launch_bounds__(SBLK) __attribute__((amdgpu_waves_per_eu(3, 3)))
void k_gru_scan(const float* __restrict__ W_hh, const float* __restrict__ b_hh,
                const float* __restrict__ gi, float* __restrict__ hs,
                float* data, int* tags) {
  const int wg  = blockIdx.x;
  const int tid = threadIdx.x;
  const bool poller = (tid < 64);
  const int lane = tid & 63;
  const int ctid = poller ? 0 : (tid - 64);   // 0..511 for compute waves
  const int row = ctid >> 5;                  // 0..15
  const int cg  = ctid & 31;                  // 0..31
  const int i   = wg * IPW + row;             // global h row

  __shared__ float hsh[2][H_DIM];
  __shared__ int cnt[2];
  if (tid == 0) { cnt[0] = 0; cnt[1] = 0; }   // visible after first barrier

  // 96 weight floats: cols {4cg + 128q + k} of rows {i, H+i, 2H+i}
  f32x4 w0[8], w1[8], w2[8];
  float bh0 = 0.f, bh1 = 0.f, bh2 = 0.f;
  if (!poller) {
    const f32x4* p0 = (const f32x4*)(W_hh + (size_t)i * H_DIM);
    const f32x4* p1 = (const f32x4*)(W_hh + (size_t)(H_DIM + i) * H_DIM);
    const f32x4* p2 = (const f32x4*)(W_hh + (size_t)(2 * H_DIM + i) * H_DIM);
#pragma unroll
    for (int q = 0; q < 8; ++q) {
      w0[q] = p0[cg + q * 32];
      w1[q] = p1[cg + q * 32];
      w2[q] = p2[cg + q * 32];
    }
    bh0 = b_hh[i]; bh1 = b_hh[H_DIM + i]; bh2 = b_hh[2 * H_DIM + i];
  }

  float hnew = 0.f;                 // carried h_{t+1} for row i (cg-replicated)
  float gir = 0.f, giz = 0.f, gin = 0.f;

  for (int t = 0; t < T_SEQ; ++t) {
    if (poller) {
      // ---- phase A, wave0: poll tags -> fetch h_t -> publish LDS ----
      {
        const int* tp = tags + (size_t)(t & 1) * 64 + lane;
        const unsigned tt = (unsigned)t;
        unsigned v;
        int it = 0;
        while (true) {
          asm volatile("global_load_dword %0, %1, off sc0 sc1\n\ts_waitcnt vmcnt(0)"
                       : "=v"(v) : "v"(tp));
          if (__all(v == tt) || ++it > (1 << 16)) break;
        }
      }
      {
        const float* dp = data + (size_t)(t & 1) * H_DIM + lane * 16;
        f32x4 d0, d1, d2, d3;
        asm volatile(
            "global_load_dwordx4 %0, %4, off sc0 sc1\n\t"
            "global_load_dwordx4 %1, %4, off offset:16 sc0 sc1\n\t"
            "global_load_dwordx4 %2, %4, off offset:32 sc0 sc1\n\t"
            "global_load_dwordx4 %3, %4, off offset:48 sc0 sc1\n\t"
            "s_waitcnt vmcnt(0)"
            : "=v"(d0), "=v"(d1), "=v"(d2), "=v"(d3)
            : "v"(dp));
        f32x4* hb4 = (f32x4*)hsh[t & 1];
        hb4[lane * 4 + 0] = d0;
        hb4[lane * 4 + 1] = d1;
        hb4[lane * 4 + 2] = d2;
        hb4[lane * 4 + 3] = d3;
      }
    } else {
      // ---- phase A, compute waves: publish h_t to mailbox, release tag ----
      if (t > 0) {
        if (cg == 0)
          __hip_atomic_store(&data[(size_t)(t & 1) * H_DIM + i], hnew,
                             __ATOMIC_RELAXED, __HIP_MEMORY_SCOPE_AGENT);
        asm volatile("s_waitcnt vmcnt(0)" ::: "memory");   // own stores committed
        if ((ctid & 63) == 0) {                            // lane0 of each wave
          int old = __hip_atomic_fetch_add(&cnt[t & 1], 1, __ATOMIC_RELAXED,
                                           __HIP_MEMORY_SCOPE_WORKGROUP);
          if (old == 7) {                                  // 8th (last) wave
            cnt[t & 1] = 0;                                // reset for t+2
            __hip_atomic_store(&tags[(size_t)(t & 1) * 64 + wg], t,
                               __ATOMIC_RELAXED, __HIP_MEMORY_SCOPE_AGENT);
          }
        }
        if (cg == 0)
          hs[(size_t)(t - 1) * H_DIM + i] = hnew;          // post-drain, lazy
      }
      // gi prefetch for phase B (completes while wave0 fetches/publishes)
      gir = gi[(size_t)t * N3H + i];
      giz = gi[(size_t)t * N3H + H_DIM + i];
      gin = gi[(size_t)t * N3H + 2 * H_DIM + i];
      // pin weights: asm "rewrites" them -> reload from W_hh illegal
      asm volatile("" : "+v"(w0[0]), "+v"(w0[1]), "+v"(w0[2]), "+v"(w0[3]),
                        "+v"(w0[4]), "+v"(w0[5]), "+v"(w0[6]), "+v"(w0[7]),
                        "+v"(w1[0]), "+v"(w1[1]), "+v"(w1[2]), "+v"(w1[3]),
                        "+v"(w1[4]), "+v"(w1[5]), "+v"(w1[6]), "+v"(w1[7]),
                        "+v"(w2[0]), "+v"(w2[1]), "+v"(w2[2]), "+v"(w2[3]),
                        "+v"(w2[4]), "+v"(w2[5]), "+v"(w2[6]), "+v"(w2[7]));
    }

    __syncthreads();   // the single textual barrier per iteration

    if (!poller) {
      // ---- phase B: h_{t+1} from LDS h_t ----
      const float* hb = hsh[t & 1];
      const f32x4* hb4 = (const f32x4*)hb;
      float a0 = 0.f, a1 = 0.f, a2 = 0.f;
#pragma unroll
      for (int q = 0; q < 8; ++q) {
        f32x4 hv = hb4[cg + q * 32];   // 32 consecutive 16B slots: conflict-free
        a0 = fmaf(w0[q][0], hv[0], a0); a0 = fmaf(w0[q][1], hv[1], a0);
        a0 = fmaf(w0[q][2], hv[2], a0); a0 = fmaf(w0[q][3], hv[3], a0);
        a1 = fmaf(w1[q][0], hv[0], a1); a1 = fmaf(w1[q][1], hv[1], a1);
        a1 = fmaf(w1[q][2], hv[2], a1); a1 = fmaf(w1[q][3], hv[3], a1);
        a2 = fmaf(w2[q][0], hv[0], a2); a2 = fmaf(w2[q][1], hv[1], a2);
        a2 = fmaf(w2[q][2], hv[2], a2); a2 = fmaf(w2[q][3], hv[3], a2);
      }
#pragma unroll
      for (int off = 16; off >= 1; off >>= 1) {   // reduce across 32-lane group
        a0 += __shfl_xor(a0, off, 64);
        a1 += __shfl_xor(a1, off, 64);
        a2 += __shfl_xor(a2, off, 64);
      }
      const float r = 1.f / (1.f + __expf(-(gir + a0 + bh0)));
      const float z = 1.f / (1.f + __expf(-(giz + a1 + bh1)));
      const float nx = gin + r * (a2 + bh2);
      const float e2 = __expf(-2.f * fabsf(nx));
      float n = (1.f - e2) / (1.f + e2);
      n = (nx < 0.f) ? -n : n;
      const float hold = hb[i];
      hnew = (1.f - z) * n + z * hold;
    }
  }
  // epilogue: last hidden state
  if (!poller && cg == 0)
    hs[(size_t)(T_SEQ - 1) * H_DIM + i] = hnew;
}

// ---------------- tag head: hs @ W_out^T + b_out, log_softmax ----------------
__global__ __launch_bounds__(256) void k_out(
    const float* __restrict__ hs, const float* __restrict__ W_out,
    const float* __restrict__ b_out, float* __restrict__ out) {
  const int t = blockIdx.x;
  const int tid = threadIdx.x;
  const int wv = tid >> 6, lane = tid & 63;
  __shared__ float xs[H_DIM];
  __shared__ float tagv[64];
  ((float4*)xs)[tid] = ((const float4*)(hs + (size_t)t * H_DIM))[tid];
  __syncthreads();
  for (int g = wv; g < VTAGS; g += 4) {
    const float4* wr = (const float4*)(W_out + (size_t)g * H_DIM);
    const float4* xr = (const float4*)xs;
    float s = 0.f;
#pragma unroll
    for (int q = 0; q < 4; ++q) {
      float4 a = wr[lane * 4 + q];
      float4 b = xr[lane * 4 + q];
      s += a.x * b.x + a.y * b.y + a.z * b.z + a.w * b.w;
    }
#pragma unroll
    for (int off = 1; off < 64; off <<= 1) s += __shfl_xor(s, off, 64);
    if (lane == 0) tagv[g] = s + b_out[g];
  }
  __syncthreads();
  if (tid < 64) {
    const float v = (tid < VTAGS) ? tagv[tid] : -1e30f;
    float m = v;
#pragma unroll
    for (int off = 1; off < 64; off <<= 1) m = fmaxf(m, __shfl_xor(m, off, 64));
    float e = (tid < VTAGS) ? __expf(v - m) : 0.f;
    float se = e;
#pragma unroll
    for (int off = 1; off < 64; off <<= 1) se += __shfl_xor(se, off, 64);
    const float lse = logf(se);
    if (tid < VTAGS) out[(size_t)t * VTAGS + tid] = v - m - lse;
  }
}

extern "C" void kernel_launch(void* const* d_in, const int* in_sizes, int n_in,
                              void* d_out, int out_size, void* d_ws, size_t ws_size,
                              hipStream_t stream) {
  const int* sent    = (const int*)d_in[0];
  const float* emb   = (const float*)d_in[1];
  const float* W_ih  = (const float*)d_in[2];
  const float* W_hh  = (const float*)d_in[3];
  const float* b_ih  = (const float*)d_in[4];
  const float* b_hh  = (const float*)d_in[5];
  const float* W_out = (const float*)d_in[6];
  const float* b_out = (const float*)d_in[7];
  float* out = (float*)d_out;

  char* ws = (char*)d_ws;
  const size_t OFF_GI = 0;
  const size_t OFF_B  = (size_t)T_SEQ * N3H * 4;            // 24 MB
  const size_t OFF_XB = OFF_B;
  const size_t OFF_WB = OFF_B + (size_t)T_SEQ * E_DIM * 2;  // +4 MB
  const size_t OFF_HS = OFF_B;                              // reuse after GEMM
  const size_t OFF_DT = OFF_B + 10485760;                   // data[2][1024] f32
  const size_t OFF_TG = OFF_DT + 2 * H_DIM * 4;             // tags[2][64] int
  const size_t NEED = OFF_TG + 2 * 64 * 4;
  if (ws_size < NEED) return;

  float* gi = (float*)(ws + OFF_GI);
  unsigned short* Xb = (unsigned short*)(ws + OFF_XB);
  unsigned short* Wb = (unsigned short*)(ws + OFF_WB);
  float* hs = (float*)(ws + OFF_HS);
  float* data = (float*)(ws + OFF_DT);
  int* tags = (int*)(ws + OFF_TG);

  // zero data (h0=0) + tags (step 0), contiguous; re-run on every graph replay
  (void)hipMemsetAsync(ws + OFF_DT, 0, 2 * H_DIM * 4 + 2 * 64 * 4, stream);

  k_gather_cast<<<T_SEQ, 256, 0, stream>>>(sent, emb, Xb);
  k_cast_w<<<N3H, 256, 0, stream>>>(W_ih, Wb);
  k_gemm_gi<<<dim3(N3H / 128, T_SEQ / 128), 256, 0, stream>>>(Xb, Wb, b_ih, gi);
  k_gru_scan<<<NWG, SBLK, 0, stream>>>(W_hh, b_hh, gi, hs, data, tags);
  k_out<<<T_SEQ, 256, 0, stream>>>(hs, W_out, b_out, out);
}

// Round 15
// 5553.285 us; speedup vs baseline: 1.7352x; 1.5878x over previous
//
#include <hip/hip_runtime.h>
#include <hip/hip_bf16.h>

// GRU tagger. T=2048, E=H=1024, 3H=3072, TAGS=50.
// R15 = R10 (best: split tag/data mailbox, wave0 poll+bulk fetch, 2 barriers)
//       + strided fetch/publish: lane l fetches float4s {l, l+64, l+128, l+192}
//       (coalesced, offset:1024/2048/3072) and stores them at hb4[l+64q] ->
//       every ds_write_b128 has lanes on consecutive 16B slots = conflict-free
//       (was 32-way, SQ_LDS_BANK_CONFLICT 1.26e7). Memory image identical.

#define T_SEQ 2048
#define E_DIM 1024
#define H_DIM 1024
#define N3H   3072
#define VTAGS 50
#define VOCAB 50257
#define NWG   64
#define IPW   (H_DIM / NWG)   // 16 h-rows per workgroup
#define SBLK  512

typedef short bf16x8 __attribute__((ext_vector_type(8)));
typedef float f32x4  __attribute__((ext_vector_type(4)));

__device__ inline unsigned short f2bf_rne(float f) {
  unsigned int u = __float_as_uint(f);
  u += 0x7FFFu + ((u >> 16) & 1u);
  return (unsigned short)(u >> 16);
}

// ---------------- embedding gather + cast to bf16 ----------------
__global__ __launch_bounds__(256) void k_gather_cast(
    const int* __restrict__ sent, const float* __restrict__ emb,
    unsigned short* __restrict__ Xb) {
  const int t = blockIdx.x;
  int row = sent[t];
  row = (row < 0) ? 0 : ((row >= VOCAB) ? VOCAB - 1 : row);
  const float4* src = (const float4*)(emb + (size_t)row * E_DIM);
  float4 v = src[threadIdx.x];
  ushort4 o;
  o.x = f2bf_rne(v.x); o.y = f2bf_rne(v.y); o.z = f2bf_rne(v.z); o.w = f2bf_rne(v.w);
  ((ushort4*)(Xb + (size_t)t * E_DIM))[threadIdx.x] = o;
}

__global__ __launch_bounds__(256) void k_cast_w(
    const float* __restrict__ W, unsigned short* __restrict__ Wb) {
  const int r = blockIdx.x;
  const float4* src = (const float4*)(W + (size_t)r * E_DIM);
  float4 v = src[threadIdx.x];
  ushort4 o;
  o.x = f2bf_rne(v.x); o.y = f2bf_rne(v.y); o.z = f2bf_rne(v.z); o.w = f2bf_rne(v.w);
  ((ushort4*)(Wb + (size_t)r * E_DIM))[threadIdx.x] = o;
}

// ---------------- gi = X @ W_ih^T + b_ih  (bf16 MFMA, fp32 accum) ----------------
__global__ __launch_bounds__(256) void k_gemm_gi(
    const unsigned short* __restrict__ Xb, const unsigned short* __restrict__ Wb,
    const float* __restrict__ b_ih, float* __restrict__ gi) {
  const int tid = threadIdx.x;
  const int lane = tid & 63;
  const int wv = tid >> 6;
  const int m_base = blockIdx.y * 128 + (wv & 1) * 64;
  const int n_base = blockIdx.x * 128 + (wv >> 1) * 64;
  const int lr = lane & 15;
  const int kq = (lane >> 4) * 8;
  f32x4 acc[4][4] = {};
  for (int k0 = 0; k0 < E_DIM; k0 += 32) {
    bf16x8 a[4], b[4];
#pragma unroll
    for (int mi = 0; mi < 4; ++mi)
      a[mi] = *(const bf16x8*)(Xb + (size_t)(m_base + mi * 16 + lr) * E_DIM + k0 + kq);
#pragma unroll
    for (int ni = 0; ni < 4; ++ni)
      b[ni] = *(const bf16x8*)(Wb + (size_t)(n_base + ni * 16 + lr) * E_DIM + k0 + kq);
#pragma unroll
    for (int mi = 0; mi < 4; ++mi)
#pragma unroll
      for (int ni = 0; ni < 4; ++ni)
        acc[mi][ni] = __builtin_amdgcn_mfma_f32_16x16x32_bf16(a[mi], b[ni], acc[mi][ni], 0, 0, 0);
  }
  const int row_q = (lane >> 4) * 4;
#pragma unroll
  for (int mi = 0; mi < 4; ++mi) {
#pragma unroll
    for (int ni = 0; ni < 4; ++ni) {
      const int col  = n_base + ni * 16 + lr;
      const int row0 = m_base + mi * 16 + row_q;
      const float bv = b_ih[col];
#pragma unroll
      for (int rr = 0; rr < 4; ++rr)
        gi[(size_t)(row0 + rr) * N3H + col] = acc[mi][ni][rr] + bv;
    }
  }
}

// ---------------- persistent GRU scan (split mailbox, wave0 poll+fetch) ----------------
// 64 WGs x 512 thr. Thread (row=tid>>5, cg=tid&31): 96 weight floats pinned.
// Per step t: wave0 polls tags[t&1][lane]==t (2 lines/retry, 64 pollers chip-wide)
//   -> wave0 bulk-loads data[t&1] strided (lane: float4s {l,l+64,l+128,l+192})
//   -> LDS (conflict-free b128 stores) -> B1 -> all: 96 FMA + butterfly + gates
//   -> cg==0 store data[(t+1)&1][i] -> B2 (vmcnt(0) drain: stores committed)
//   -> tid0 tag store.
// Safety: tag t+1 from WG w implies w's data stores committed (B2 drain) and w
// finished reading slot t&1 (reads < B2). Slot t&1 overwritten only at step t+1
// by WGs that saw ALL tags==t+1. asm volatile order keeps bulk-load after poll.
__global__ __launch_bounds__(SBLK) __attribute__((amdgpu_waves_per_eu(2, 2)))
void k_gru_scan(const float* __restrict__ W_hh, const float* __restrict__ b_hh,
                const float* __restrict__ gi, float* __restrict__ hs,
                float* data, int* tags) {
  const int wg  = blockIdx.x;
  const int tid = threadIdx.x;
  const int row = tid >> 5;        // 0..15 : h-row within WG
  const int cg  = tid & 31;        // 0..31 : column group
  const int lane = tid & 63;
  const int i   = wg * IPW + row;  // global h row

  __shared__ float hsh[2][H_DIM];

  // 96 weight floats: cols {4cg + 128q + k} of rows {i, H+i, 2H+i}
  f32x4 w0[8], w1[8], w2[8];
  {
    const f32x4* p0 = (const f32x4*)(W_hh + (size_t)i * H_DIM);
    const f32x4* p1 = (const f32x4*)(W_hh + (size_t)(H_DIM + i) * H_DIM);
    const f32x4* p2 = (const f32x4*)(W_hh + (size_t)(2 * H_DIM + i) * H_DIM);
#pragma unroll
    for (int q = 0; q < 8; ++q) {
      w0[q] = p0[cg + q * 32];
      w1[q] = p1[cg + q * 32];
      w2[q] = p2[cg + q * 32];
    }
  }
  const float bh0 = b_hh[i], bh1 = b_hh[H_DIM + i], bh2 = b_hh[2 * H_DIM + i];

  for (int t = 0; t < T_SEQ; ++t) {
    // pin weights: asm "rewrites" them each iteration -> reload from W_hh illegal
    asm volatile("" : "+v"(w0[0]), "+v"(w0[1]), "+v"(w0[2]), "+v"(w0[3]),
                      "+v"(w0[4]), "+v"(w0[5]), "+v"(w0[6]), "+v"(w0[7]),
                      "+v"(w1[0]), "+v"(w1[1]), "+v"(w1[2]), "+v"(w1[3]),
                      "+v"(w1[4]), "+v"(w1[5]), "+v"(w1[6]), "+v"(w1[7]),
                      "+v"(w2[0]), "+v"(w2[1]), "+v"(w2[2]), "+v"(w2[3]),
                      "+v"(w2[4]), "+v"(w2[5]), "+v"(w2[6]), "+v"(w2[7]));

    // gi prefetch: issued before the poll/wait, completes under it
    const float gir = gi[(size_t)t * N3H + i];
    const float giz = gi[(size_t)t * N3H + H_DIM + i];
    const float gin = gi[(size_t)t * N3H + 2 * H_DIM + i];

    if (tid < 64) {
      // wave0: poll the 64 per-WG tags of slot t&1 (lane l watches tag[l])
      {
        const int* tp = tags + (size_t)(t & 1) * 64 + lane;
        const unsigned tt = (unsigned)t;
        unsigned v;
        int it = 0;
        while (true) {
          asm volatile("global_load_dword %0, %1, off sc0 sc1\n\ts_waitcnt vmcnt(0)"
                       : "=v"(v) : "v"(tp));
          if (__all(v == tt) || ++it > (1 << 16)) break;
        }
      }
      // strided bulk fetch: lane l reads float4s {l, l+64, l+128, l+192}
      // (each load instruction: 64 lanes cover 1024 contiguous bytes = coalesced)
      {
        const float* dp = data + (size_t)(t & 1) * H_DIM + lane * 4;
        f32x4 d0, d1, d2, d3;
        asm volatile(
            "global_load_dwordx4 %0, %4, off sc0 sc1\n\t"
            "global_load_dwordx4 %1, %4, off offset:1024 sc0 sc1\n\t"
            "global_load_dwordx4 %2, %4, off offset:2048 sc0 sc1\n\t"
            "global_load_dwordx4 %3, %4, off offset:3072 sc0 sc1\n\t"
            "s_waitcnt vmcnt(0)"
            : "=v"(d0), "=v"(d1), "=v"(d2), "=v"(d3)
            : "v"(dp));
        // publish: lanes on consecutive float4 slots per store -> conflict-free
        f32x4* hb4 = (f32x4*)hsh[t & 1];
        hb4[lane]       = d0;
        hb4[lane + 64]  = d1;
        hb4[lane + 128] = d2;
        hb4[lane + 192] = d3;
      }
    }
    __syncthreads();   // B1: h published to LDS

    const float* hb = hsh[t & 1];
    const f32x4* hb4 = (const f32x4*)hb;
    float a0 = 0.f, a1 = 0.f, a2 = 0.f;
#pragma unroll
    for (int q = 0; q < 8; ++q) {
      f32x4 hv = hb4[cg + q * 32];   // 32 consecutive 16B slots: conflict-free
      a0 = fmaf(w0[q][0], hv[0], a0); a0 = fmaf(w0[q][1], hv[1], a0);
      a0 = fmaf(w0[q][2], hv[2], a0); a0 = fmaf(w0[q][3], hv[3], a0);
      a1 = fmaf(w1[q][0], hv[0], a1); a1 = fmaf(w1[q][1], hv[1], a1);
      a1 = fmaf(w1[q][2], hv[2], a1); a1 = fmaf(w1[q][3], hv[3], a1);
      a2 = fmaf(w2[q][0], hv[0], a2); a2 = fmaf(w2[q][1], hv[1], a2);
      a2 = fmaf(w2[q][2], hv[2], a2); a2 = fmaf(w2[q][3], hv[3], a2);
    }
#pragma unroll
    for (int off = 16; off >= 1; off >>= 1) {   // reduce across 32-lane group
      a0 += __shfl_xor(a0, off, 64);
      a1 += __shfl_xor(a1, off, 64);
      a2 += __shfl_xor(a2, off, 64);
    }
    const float r = 1.f / (1.f + __expf(-(gir + a0 + bh0)));
    const float z = 1.f / (1.f + __expf(-(giz + a1 + bh1)));
    const float nx = gin + r * (a2 + bh2);
    const float e2 = __expf(-2.f * fabsf(nx));
    float n = (1.f - e2) / (1.f + e2);
    n = (nx < 0.f) ? -n : n;
    const float hold = hb[i];
    const float hnew = (1.f - z) * n + z * hold;

    if (cg == 0) {
      __hip_atomic_store(&data[(size_t)((t + 1) & 1) * H_DIM + i], hnew,
                         __ATOMIC_RELAXED, __HIP_MEMORY_SCOPE_AGENT);
      hs[(size_t)t * H_DIM + i] = hnew;   // consumed by k_out after kernel end
    }
    __syncthreads();   // B2: vmcnt(0) drained -> all 16 data stores committed
    if (tid == 0)
      __hip_atomic_store(&tags[(size_t)((t + 1) & 1) * 64 + wg], t + 1,
                         __ATOMIC_RELAXED, __HIP_MEMORY_SCOPE_AGENT);
  }
}

// ---------------- tag head: hs @ W_out^T + b_out, log_softmax ----------------
__global__ __launch_bounds__(256) void k_out(
    const float* __restrict__ hs, const float* __restrict__ W_out,
    const float* __restrict__ b_out, float* __restrict__ out) {
  const int t = blockIdx.x;
  const int tid = threadIdx.x;
  const int wv = tid >> 6, lane = tid & 63;
  __shared__ float xs[H_DIM];
  __shared__ float tagv[64];
  ((float4*)xs)[tid] = ((const float4*)(hs + (size_t)t * H_DIM))[tid];
  __syncthreads();
  for (int g = wv; g < VTAGS; g += 4) {
    const float4* wr = (const float4*)(W_out + (size_t)g * H_DIM);
    const float4* xr = (const float4*)xs;
    float s = 0.f;
#pragma unroll
    for (int q = 0; q < 4; ++q) {
      float4 a = wr[lane * 4 + q];
      float4 b = xr[lane * 4 + q];
      s += a.x * b.x + a.y * b.y + a.z * b.z + a.w * b.w;
    }
#pragma unroll
    for (int off = 1; off < 64; off <<= 1) s += __shfl_xor(s, off, 64);
    if (lane == 0) tagv[g] = s + b_out[g];
  }
  __syncthreads();
  if (tid < 64) {
    const float v = (tid < VTAGS) ? tagv[tid] : -1e30f;
    float m = v;
#pragma unroll
    for (int off = 1; off < 64; off <<= 1) m = fmaxf(m, __shfl_xor(m, off, 64));
    float e = (tid < VTAGS) ? __expf(v - m) : 0.f;
    float se = e;
#pragma unroll
    for (int off = 1; off < 64; off <<= 1) se += __shfl_xor(se, off, 64);
    const float lse = logf(se);
    if (tid < VTAGS) out[(size_t)t * VTAGS + tid] = v - m - lse;
  }
}

extern "C" void kernel_launch(void* const* d_in, const int* in_sizes, int n_in,
                              void* d_out, int out_size, void* d_ws, size_t ws_size,
                              hipStream_t stream) {
  const int* sent    = (const int*)d_in[0];
  const float* emb   = (const float*)d_in[1];
  const float* W_ih  = (const float*)d_in[2];
  const float* W_hh  = (const float*)d_in[3];
  const float* b_ih  = (const float*)d_in[4];
  const float* b_hh  = (const float*)d_in[5];
  const float* W_out = (const float*)d_in[6];
  const float* b_out = (const float*)d_in[7];
  float* out = (float*)d_out;

  char* ws = (char*)d_ws;
  const size_t OFF_GI = 0;
  const size_t OFF_B  = (size_t)T_SEQ * N3H * 4;            // 24 MB
  const size_t OFF_XB = OFF_B;
  const size_t OFF_WB = OFF_B + (size_t)T_SEQ * E_DIM * 2;  // +4 MB
  const size_t OFF_HS = OFF_B;                              // reuse after GEMM
  const size_t OFF_DT = OFF_B + 10485760;                   // data[2][1024] f32
  const size_t OFF_TG = OFF_DT + 2 * H_DIM * 4;             // tags[2][64] int
  const size_t NEED = OFF_TG + 2 * 64 * 4;
  if (ws_size < NEED) return;

  float* gi = (float*)(ws + OFF_GI);
  unsigned short* Xb = (unsigned short*)(ws + OFF_XB);
  unsigned short* Wb = (unsigned short*)(ws + OFF_WB);
  float* hs = (float*)(ws + OFF_HS);
  float* data = (float*)(ws + OFF_DT);
  int* tags = (int*)(ws + OFF_TG);

  // zero data (h0=0) + tags (step 0), contiguous; re-run on every graph replay
  (void)hipMemsetAsync(ws + OFF_DT, 0, 2 * H_DIM * 4 + 2 * 64 * 4, stream);

  k_gather_cast<<<T_SEQ, 256, 0, stream>>>(sent, emb, Xb);
  k_cast_w<<<N3H, 256, 0, stream>>>(W_ih, Wb);
  k_gemm_gi<<<dim3(N3H / 128, T_SEQ / 128), 256, 0, stream>>>(Xb, Wb, b_ih, gi);
  k_gru_scan<<<NWG, SBLK, 0, stream>>>(W_hh, b_hh, gi, hs, data, tags);
  k_out<<<T_SEQ, 256, 0, stream>>>(hs, W_out, b_out, out);
}